// Round 2
// baseline (1649.130 us; speedup 1.0000x reference)
//
#include <hip/hip_runtime.h>

#define HID 128
#define BN_EPS 1e-5f

typedef __bf16 bf16;
typedef __attribute__((ext_vector_type(8))) __bf16 bf16x8;
typedef __attribute__((ext_vector_type(4))) float f32x4;

__device__ __forceinline__ float bnrelu(float x, float a, float c) {
  return fmaxf(fmaf(a, x, c), 0.f);
}

// ---------------- CSR build ----------------
__global__ void hist_k(const int* __restrict__ dst, int* __restrict__ cnt, int E) {
  int i = blockIdx.x * blockDim.x + threadIdx.x;
  if (i < E) atomicAdd(&cnt[dst[i]], 1);
}

__global__ void scan_k(int* __restrict__ cnt_cursor, int* __restrict__ row_start, int Nn) {
  __shared__ int wtot[16];
  __shared__ int carry_s;
  int tid = threadIdx.x, lane = tid & 63, wv = tid >> 6;
  int offset = 0;
  for (int base = 0; base < Nn; base += 1024) {
    int i = base + tid;
    int v = (i < Nn) ? cnt_cursor[i] : 0;
    int x = v;
#pragma unroll
    for (int d = 1; d < 64; d <<= 1) { int t = __shfl_up(x, d, 64); if (lane >= d) x += t; }
    if (lane == 63) wtot[wv] = x;
    __syncthreads();
    if (wv == 0) {
      int wval = (lane < 16) ? wtot[lane] : 0;
#pragma unroll
      for (int d = 1; d < 16; d <<= 1) { int t = __shfl_up(wval, d, 64); if (lane >= d) wval += t; }
      if (lane < 16) wtot[lane] = wval;
      if (lane == 15) carry_s = wval;
    }
    __syncthreads();
    int wexcl = (wv == 0) ? 0 : wtot[wv - 1];
    int excl = x + wexcl - v;                 // exclusive within chunk
    if (i < Nn) { int st = offset + excl; row_start[i] = st; cnt_cursor[i] = st; }
    int ctot = carry_s;
    __syncthreads();
    offset += ctot;
  }
  if (tid == 0) row_start[Nn] = offset;
}

__global__ void fill_k(const int* __restrict__ src, const int* __restrict__ dst,
                       int* __restrict__ cursor, int* __restrict__ csr, int E) {
  int i = blockIdx.x * blockDim.x + threadIdx.x;
  if (i < E) { int p = atomicAdd(&cursor[dst[i]], 1); csr[p] = src[i]; }
}

// ---------------- aggregation (+z, bf16 output) ----------------
// MODE 0: h = H (raw).  MODE 1: h = relu(a3*relu(a2*x+c2)+c3)
template<int MODE>
__global__ __launch_bounds__(256)
void agg_k(const float* __restrict__ H,
           const float* __restrict__ a2, const float* __restrict__ c2,
           const float* __restrict__ a3, const float* __restrict__ c3,
           const int* __restrict__ row_start, const int* __restrict__ csr,
           bf16* __restrict__ Z, int Nn) {
  int wv = threadIdx.x >> 6, lane = threadIdx.x & 63;
  int n = blockIdx.x * 4 + wv;
  if (n >= Nn) return;
  int c0 = lane * 2;
  float A2x = 0, A2y = 0, C2x = 0, C2y = 0, A3x = 0, A3y = 0, C3x = 0, C3y = 0;
  if (MODE) {
    float2 t;
    t = *(const float2*)(a2 + c0); A2x = t.x; A2y = t.y;
    t = *(const float2*)(c2 + c0); C2x = t.x; C2y = t.y;
    t = *(const float2*)(a3 + c0); A3x = t.x; A3y = t.y;
    t = *(const float2*)(c3 + c0); C3x = t.x; C3y = t.y;
  }
  int beg = row_start[n], end = row_start[n + 1];
  float inv = 1.f / fmaxf((float)(end - beg), 1.f);
  float ax = 0.f, ay = 0.f;
  for (int j = beg; j < end; ++j) {
    int s = csr[j];
    float2 v = *(const float2*)(H + (size_t)s * HID + c0);
    float hx = v.x, hy = v.y;
    if (MODE) {
      hx = bnrelu(bnrelu(hx, A2x, C2x), A3x, C3x);
      hy = bnrelu(bnrelu(hy, A2y, C2y), A3y, C3y);
    }
    ax += hx; ay += hy;
  }
  float2 hn = *(const float2*)(H + (size_t)n * HID + c0);
  float hx = hn.x, hy = hn.y;
  if (MODE) {
    hx = bnrelu(bnrelu(hx, A2x, C2x), A3x, C3x);
    hy = bnrelu(bnrelu(hy, A2y, C2y), A3y, C3y);
  }
  float zx = hx + ax * inv, zy = hy + ay * inv;
  union { bf16 h[2]; unsigned u; } pk;
  pk.h[0] = (bf16)zx; pk.h[1] = (bf16)zy;
  *(unsigned*)((char*)Z + ((size_t)n * HID + c0) * 2) = pk.u;
}

// ---------------- GEMM: C[NrowsxHID] = A @ W^T  (W row-major [out][in]) ----------------
// AMODE 0: A is bf16 (Z). AMODE 1: A is f32, transformed relu(a*x+c) then bf16.
template<int AMODE>
__global__ __launch_bounds__(256)
void gemm_k(const void* __restrict__ Asrc,
            const float* __restrict__ acoef, const float* __restrict__ ccoef,
            const float* __restrict__ W, float* __restrict__ C, int Nrows) {
  int wv = threadIdx.x >> 6, lane = threadIdx.x & 63;
  int lm = lane & 15, lg = lane >> 4;
  int rowbase = blockIdx.x * 128 + wv * 32;
  f32x4 acc[2][8] = {};
#pragma unroll
  for (int kk = 0; kk < 4; ++kk) {
    int kb = kk * 32 + lg * 8;
    bf16x8 af[2];
    if (AMODE == 0) {
      const bf16* Zp = (const bf16*)Asrc;
#pragma unroll
      for (int rt = 0; rt < 2; ++rt) {
        int row = rowbase + rt * 16 + lm; if (row > Nrows - 1) row = Nrows - 1;
        af[rt] = *(const bf16x8*)(Zp + (size_t)row * HID + kb);
      }
    } else {
      const float* Tp = (const float*)Asrc;
      float4 a0 = *(const float4*)(acoef + kb), a1 = *(const float4*)(acoef + kb + 4);
      float4 q0 = *(const float4*)(ccoef + kb), q1 = *(const float4*)(ccoef + kb + 4);
#pragma unroll
      for (int rt = 0; rt < 2; ++rt) {
        int row = rowbase + rt * 16 + lm; if (row > Nrows - 1) row = Nrows - 1;
        const float* p = Tp + (size_t)row * HID + kb;
        float4 x0 = *(const float4*)p, x1 = *(const float4*)(p + 4);
        bf16x8 f;
        f[0] = (bf16)bnrelu(x0.x, a0.x, q0.x); f[1] = (bf16)bnrelu(x0.y, a0.y, q0.y);
        f[2] = (bf16)bnrelu(x0.z, a0.z, q0.z); f[3] = (bf16)bnrelu(x0.w, a0.w, q0.w);
        f[4] = (bf16)bnrelu(x1.x, a1.x, q1.x); f[5] = (bf16)bnrelu(x1.y, a1.y, q1.y);
        f[6] = (bf16)bnrelu(x1.z, a1.z, q1.z); f[7] = (bf16)bnrelu(x1.w, a1.w, q1.w);
        af[rt] = f;
      }
    }
    bf16x8 bfr[8];
#pragma unroll
    for (int ct = 0; ct < 8; ++ct) {
      const float* wp = W + (size_t)(ct * 16 + lm) * HID + kb;
      float4 w0 = *(const float4*)wp, w1 = *(const float4*)(wp + 4);
      bf16x8 f;
      f[0] = (bf16)w0.x; f[1] = (bf16)w0.y; f[2] = (bf16)w0.z; f[3] = (bf16)w0.w;
      f[4] = (bf16)w1.x; f[5] = (bf16)w1.y; f[6] = (bf16)w1.z; f[7] = (bf16)w1.w;
      bfr[ct] = f;
    }
#pragma unroll
    for (int rt = 0; rt < 2; ++rt)
#pragma unroll
      for (int ct = 0; ct < 8; ++ct)
        acc[rt][ct] = __builtin_amdgcn_mfma_f32_16x16x32_bf16(af[rt], bfr[ct], acc[rt][ct], 0, 0, 0);
  }
#pragma unroll
  for (int rt = 0; rt < 2; ++rt)
#pragma unroll
    for (int ct = 0; ct < 8; ++ct) {
      int col = ct * 16 + lm;
#pragma unroll
      for (int i = 0; i < 4; ++i) {
        int row = rowbase + rt * 16 + lg * 4 + i;
        if (row < Nrows) C[(size_t)row * HID + col] = acc[rt][ct][i];
      }
    }
}

// ---------------- BN stats ----------------
// MODE 0: x.  MODE 1: x' = relu(a*x+c)
template<int MODE>
__global__ __launch_bounds__(256)
void stats_k(const float* __restrict__ T, const float* __restrict__ a, const float* __restrict__ c,
             float* __restrict__ accum, int Nrows) {
  int col = threadIdx.x & 127;
  int half = threadIdx.x >> 7;
  float av = 0.f, cv = 0.f;
  if (MODE) { av = a[col]; cv = c[col]; }
  float s = 0.f, sq = 0.f;
  for (int r = blockIdx.x * 2 + half; r < Nrows; r += gridDim.x * 2) {
    float x = T[(size_t)r * HID + col];
    if (MODE) x = fmaxf(fmaf(av, x, cv), 0.f);
    s += x; sq = fmaf(x, x, sq);
  }
  __shared__ float sb[256], qb[256];
  sb[threadIdx.x] = s; qb[threadIdx.x] = sq;
  __syncthreads();
  if (half == 0) {
    s += sb[threadIdx.x + 128]; sq += qb[threadIdx.x + 128];
    atomicAdd(&accum[col], s); atomicAdd(&accum[128 + col], sq);
  }
}

__global__ void fin_k(const float* __restrict__ accum, const float* __restrict__ g,
                      const float* __restrict__ b,
                      float* __restrict__ a, float* __restrict__ c, float invN) {
  int i = threadIdx.x;
  float mu = accum[i] * invN;
  float var = fmaxf(accum[128 + i] * invN - mu * mu, 0.f);
  float rs = rsqrtf(var + BN_EPS);
  float av = g[i] * rs;
  a[i] = av;
  c[i] = fmaf(-av, mu, b[i]);
}

// ---------------- fused link predictor ----------------
__global__ __launch_bounds__(256)
void pred_k(const float* __restrict__ T, const float* __restrict__ a2, const float* __restrict__ c2,
            const int* __restrict__ ps, const int* __restrict__ pd,
            const int* __restrict__ ns, const int* __restrict__ nd,
            const float* __restrict__ W1p, const float* __restrict__ b1p,
            const float* __restrict__ W2p, const float* __restrict__ b2p,
            const float* __restrict__ w3, const float* __restrict__ b3,
            float* __restrict__ out, int Pn) {
  __shared__ bf16 At[128 * 128];  // 32KB, XOR-swizzled
  int tid = threadIdx.x;
  int q0 = blockIdx.x * 128;
  {
    int r = tid >> 1;
    int q = q0 + r;
    int cb = (tid & 1) * 64;
    if (q < 2 * Pn) {
      int s, d;
      if (q < Pn) { s = ps[q]; d = pd[q]; } else { s = ns[q - Pn]; d = nd[q - Pn]; }
      const float* rs_ = T + (size_t)s * HID;
      const float* rd_ = T + (size_t)d * HID;
      for (int c = cb; c < cb + 64; c += 4) {
        float4 xs = *(const float4*)(rs_ + c);
        float4 xd = *(const float4*)(rd_ + c);
        float4 av = *(const float4*)(a2 + c);
        float4 cv = *(const float4*)(c2 + c);
        float t0 = bnrelu(xs.x, av.x, cv.x) * bnrelu(xd.x, av.x, cv.x);
        float t1 = bnrelu(xs.y, av.y, cv.y) * bnrelu(xd.y, av.y, cv.y);
        float t2 = bnrelu(xs.z, av.z, cv.z) * bnrelu(xd.z, av.z, cv.z);
        float t3 = bnrelu(xs.w, av.w, cv.w) * bnrelu(xd.w, av.w, cv.w);
        union { bf16 h[4]; unsigned long long u; } pk;
        pk.h[0] = (bf16)t0; pk.h[1] = (bf16)t1; pk.h[2] = (bf16)t2; pk.h[3] = (bf16)t3;
        unsigned addr = (unsigned)(r * 256 + c * 2);
        addr ^= (unsigned)((r & 7) << 4);
        *(unsigned long long*)((char*)At + addr) = pk.u;
      }
    } else {
      for (int c = cb; c < cb + 64; c += 4) {
        unsigned addr = (unsigned)(r * 256 + c * 2);
        addr ^= (unsigned)((r & 7) << 4);
        *(unsigned long long*)((char*)At + addr) = 0ull;
      }
    }
  }
  __syncthreads();
  int wv = tid >> 6, lane = tid & 63;
  int lm = lane & 15, lg = lane >> 4;
  const f32x4 vzero = {0.f, 0.f, 0.f, 0.f};
  f32x4 acc[2][8];
#pragma unroll
  for (int r = 0; r < 2; ++r) for (int c = 0; c < 8; ++c) acc[r][c] = vzero;
  // ---- layer 1 ----
#pragma unroll
  for (int kk = 0; kk < 4; ++kk) {
    bf16x8 af[2];
#pragma unroll
    for (int rt = 0; rt < 2; ++rt) {
      int row = wv * 32 + rt * 16 + lm;
      unsigned addr = (unsigned)(row * 256 + kk * 64 + lg * 16);
      addr ^= (unsigned)((row & 7) << 4);
      af[rt] = *(const bf16x8*)((char*)At + addr);
    }
    bf16x8 bfr[8];
#pragma unroll
    for (int ct = 0; ct < 8; ++ct) {
      const float* wp = W1p + (size_t)(ct * 16 + lm) * HID + kk * 32 + lg * 8;
      float4 w0 = *(const float4*)wp, w1 = *(const float4*)(wp + 4);
      bf16x8 f;
      f[0] = (bf16)w0.x; f[1] = (bf16)w0.y; f[2] = (bf16)w0.z; f[3] = (bf16)w0.w;
      f[4] = (bf16)w1.x; f[5] = (bf16)w1.y; f[6] = (bf16)w1.z; f[7] = (bf16)w1.w;
      bfr[ct] = f;
    }
#pragma unroll
    for (int rt = 0; rt < 2; ++rt)
#pragma unroll
      for (int ct = 0; ct < 8; ++ct)
        acc[rt][ct] = __builtin_amdgcn_mfma_f32_16x16x32_bf16(af[rt], bfr[ct], acc[rt][ct], 0, 0, 0);
  }
  __syncthreads();   // all LDS reads of stage-A done before overwrite
#pragma unroll
  for (int rt = 0; rt < 2; ++rt)
#pragma unroll
    for (int ct = 0; ct < 8; ++ct) {
      int col = ct * 16 + lm;
      float bb = b1p[col];
#pragma unroll
      for (int i = 0; i < 4; ++i) {
        int row = wv * 32 + rt * 16 + lg * 4 + i;
        float v = fmaxf(acc[rt][ct][i] + bb, 0.f);
        unsigned addr = (unsigned)(row * 256 + col * 2);
        addr ^= (unsigned)((row & 7) << 4);
        *(bf16*)((char*)At + addr) = (bf16)v;
      }
    }
  __syncthreads();
  // ---- layer 2 ----
#pragma unroll
  for (int r = 0; r < 2; ++r) for (int c = 0; c < 8; ++c) acc[r][c] = vzero;
#pragma unroll
  for (int kk = 0; kk < 4; ++kk) {
    bf16x8 af[2];
#pragma unroll
    for (int rt = 0; rt < 2; ++rt) {
      int row = wv * 32 + rt * 16 + lm;
      unsigned addr = (unsigned)(row * 256 + kk * 64 + lg * 16);
      addr ^= (unsigned)((row & 7) << 4);
      af[rt] = *(const bf16x8*)((char*)At + addr);
    }
    bf16x8 bfr[8];
#pragma unroll
    for (int ct = 0; ct < 8; ++ct) {
      const float* wp = W2p + (size_t)(ct * 16 + lm) * HID + kk * 32 + lg * 8;
      float4 w0 = *(const float4*)wp, w1 = *(const float4*)(wp + 4);
      bf16x8 f;
      f[0] = (bf16)w0.x; f[1] = (bf16)w0.y; f[2] = (bf16)w0.z; f[3] = (bf16)w0.w;
      f[4] = (bf16)w1.x; f[5] = (bf16)w1.y; f[6] = (bf16)w1.z; f[7] = (bf16)w1.w;
      bfr[ct] = f;
    }
#pragma unroll
    for (int rt = 0; rt < 2; ++rt)
#pragma unroll
      for (int ct = 0; ct < 8; ++ct)
        acc[rt][ct] = __builtin_amdgcn_mfma_f32_16x16x32_bf16(af[rt], bfr[ct], acc[rt][ct], 0, 0, 0);
  }
  // ---- w3 dot + reduce ----
  float b2v[8], w3v[8];
#pragma unroll
  for (int ct = 0; ct < 8; ++ct) { b2v[ct] = b2p[ct * 16 + lm]; w3v[ct] = w3[ct * 16 + lm]; }
  float b3s = b3[0];
#pragma unroll
  for (int rt = 0; rt < 2; ++rt) {
#pragma unroll
    for (int i = 0; i < 4; ++i) {
      float p = 0.f;
#pragma unroll
      for (int ct = 0; ct < 8; ++ct)
        p += fmaxf(acc[rt][ct][i] + b2v[ct], 0.f) * w3v[ct];
      p += __shfl_xor(p, 1); p += __shfl_xor(p, 2);
      p += __shfl_xor(p, 4); p += __shfl_xor(p, 8);
      int row = wv * 32 + rt * 16 + lg * 4 + i;
      int q = q0 + row;
      if (lm == 0 && q < 2 * Pn) out[q] = p + b3s;
    }
  }
}

// ---------------- launcher ----------------
extern "C" void kernel_launch(void* const* d_in, const int* in_sizes, int n_in,
                              void* d_out, int out_size, void* d_ws, size_t ws_size,
                              hipStream_t stream) {
  const float* x  = (const float*)d_in[0];
  const int* src  = (const int*)d_in[1];
  const int* dst  = (const int*)d_in[2];
  const int* ps   = (const int*)d_in[3];
  const int* pd   = (const int*)d_in[4];
  const int* ns   = (const int*)d_in[5];
  const int* nd   = (const int*)d_in[6];
  const float* W0 = (const float*)d_in[7];
  const float* W1 = (const float*)d_in[8];
  const float* g_mlp   = (const float*)d_in[9];
  const float* b_mlp   = (const float*)d_in[10];
  const float* g_apply = (const float*)d_in[11];
  const float* b_apply = (const float*)d_in[12];
  const float* g_out   = (const float*)d_in[13];
  const float* b_out   = (const float*)d_in[14];
  const float* pW1 = (const float*)d_in[15];
  const float* pb1 = (const float*)d_in[16];
  const float* pW2 = (const float*)d_in[17];
  const float* pb2 = (const float*)d_in[18];
  const float* pW3 = (const float*)d_in[19];
  const float* pb3 = (const float*)d_in[20];
  float* out = (float*)d_out;

  const int N = in_sizes[0] / HID;
  const int E = in_sizes[1];
  const int P = in_sizes[3];

  char* w = (char*)d_ws;
  size_t off = 0;
  auto alloc = [&](size_t bytes) -> void* {
    void* p = w + off;
    off = (off + bytes + 255) & ~(size_t)255;
    return p;
  };
  bf16*  Z  = (bf16*)alloc((size_t)N * HID * 2);
  float* TA = (float*)alloc((size_t)N * HID * 4);
  float* TB = (float*)alloc((size_t)N * HID * 4);
  int*   csr = (int*)alloc((size_t)E * 4);
  int*   row_start = (int*)alloc((size_t)(N + 1) * 4);
  size_t zoff = off;
  int*   cursor = (int*)alloc((size_t)N * 4);
  float* accum  = (float*)alloc(9 * 256 * 4);
  size_t zbytes = off - zoff;
  float* coefA = (float*)alloc(9 * 128 * 4);
  float* coefC = (float*)alloc(9 * 128 * 4);
  (void)ws_size; (void)n_in; (void)out_size;

  hipMemsetAsync(w + zoff, 0, zbytes, stream);
  int gridE = (E + 255) / 256;
  hist_k<<<gridE, 256, 0, stream>>>(dst, cursor, E);
  scan_k<<<1, 1024, 0, stream>>>(cursor, row_start, N);
  fill_k<<<gridE, 256, 0, stream>>>(src, dst, cursor, csr, E);

  int gridN4 = (N + 3) / 4;
  int gridG  = (N + 127) / 128;
  const float invN = 1.f / (float)N;

  for (int l = 0; l < 3; ++l) {
    int s0 = l * 3 + 0, s1 = l * 3 + 1, s2 = l * 3 + 2;
    if (l == 0)
      agg_k<0><<<gridN4, 256, 0, stream>>>(x, nullptr, nullptr, nullptr, nullptr,
                                           row_start, csr, Z, N);
    else {
      int p1 = (l - 1) * 3 + 1, p2 = (l - 1) * 3 + 2;
      agg_k<1><<<gridN4, 256, 0, stream>>>(TB, coefA + p1 * 128, coefC + p1 * 128,
                                           coefA + p2 * 128, coefC + p2 * 128,
                                           row_start, csr, Z, N);
    }
    gemm_k<0><<<gridG, 256, 0, stream>>>(Z, nullptr, nullptr, W0 + (size_t)l * HID * HID, TA, N);
    stats_k<0><<<512, 256, 0, stream>>>(TA, nullptr, nullptr, accum + s0 * 256, N);
    fin_k<<<1, 128, 0, stream>>>(accum + s0 * 256, g_mlp + l * HID, b_mlp + l * HID,
                                 coefA + s0 * 128, coefC + s0 * 128, invN);
    gemm_k<1><<<gridG, 256, 0, stream>>>(TA, coefA + s0 * 128, coefC + s0 * 128,
                                         W1 + (size_t)l * HID * HID, TB, N);
    stats_k<0><<<512, 256, 0, stream>>>(TB, nullptr, nullptr, accum + s1 * 256, N);
    fin_k<<<1, 128, 0, stream>>>(accum + s1 * 256, g_apply + l * HID, b_apply + l * HID,
                                 coefA + s1 * 128, coefC + s1 * 128, invN);
    if (l < 2) {
      stats_k<1><<<512, 256, 0, stream>>>(TB, coefA + s1 * 128, coefC + s1 * 128,
                                          accum + s2 * 256, N);
      fin_k<<<1, 128, 0, stream>>>(accum + s2 * 256, g_out + l * HID, b_out + l * HID,
                                   coefA + s2 * 128, coefC + s2 * 128, invN);
    }
  }
  int gridP = (2 * P + 127) / 128;
  pred_k<<<gridP, 256, 0, stream>>>(TB, coefA + 7 * 128, coefC + 7 * 128,
                                    ps, pd, ns, nd, pW1, pb1, pW2, pb2, pW3, pb3, out, P);
}

// Round 3
// 1107.031 us; speedup vs baseline: 1.4897x; 1.4897x over previous
//
#include <hip/hip_runtime.h>

#define HID 128
#define BN_EPS 1e-5f

typedef __bf16 bf16;
typedef __attribute__((ext_vector_type(8))) __bf16 bf16x8;
typedef __attribute__((ext_vector_type(4))) float f32x4;

__device__ __forceinline__ float bnrelu(float x, float a, float c) {
  return fmaxf(fmaf(a, x, c), 0.f);
}

// ---------------- CSR build ----------------
__global__ void hist_k(const int* __restrict__ dst, int* __restrict__ cnt, int E) {
  int i = blockIdx.x * blockDim.x + threadIdx.x;
  if (i < E) atomicAdd(&cnt[dst[i]], 1);
}

// block partial sums (1024 elems / block)
__global__ __launch_bounds__(256)
void scan1_k(const int* __restrict__ cnt, int* __restrict__ bsum, int Nn) {
  __shared__ int red[4];
  int tid = threadIdx.x;
  int base = blockIdx.x * 1024;
  int s = 0;
#pragma unroll
  for (int u = 0; u < 4; ++u) {
    int i = base + u * 256 + tid;
    if (i < Nn) s += cnt[i];
  }
#pragma unroll
  for (int d = 1; d < 64; d <<= 1) s += __shfl_xor(s, d, 64);
  int lane = tid & 63, wv = tid >> 6;
  if (lane == 0) red[wv] = s;
  __syncthreads();
  if (tid == 0) bsum[blockIdx.x] = red[0] + red[1] + red[2] + red[3];
}

// exclusive scan of block sums, in place (single wave)
__global__ void scan2_k(int* __restrict__ bsum, int G) {
  int lane = threadIdx.x;
  int carry = 0;
  for (int base = 0; base < G; base += 64) {
    int i = base + lane;
    int v = (i < G) ? bsum[i] : 0;
    int x = v;
#pragma unroll
    for (int d = 1; d < 64; d <<= 1) { int t = __shfl_up(x, d, 64); if (lane >= d) x += t; }
    if (i < G) bsum[i] = carry + x - v;
    carry += __shfl(x, 63, 64);
  }
}

// final scan: row_start + cursor
__global__ __launch_bounds__(256)
void scan3_k(const int* __restrict__ cnt, const int* __restrict__ boff,
             int* __restrict__ row_start, int* __restrict__ cursor, int Nn, int E) {
  __shared__ int wtot[4];
  int tid = threadIdx.x, lane = tid & 63, wv = tid >> 6;
  int i0 = blockIdx.x * 1024 + tid * 4;
  int t0 = 0, t1 = 0, t2 = 0, t3 = 0;
  if (i0 + 3 < Nn) {
    int4 v = *(const int4*)(cnt + i0);
    t0 = v.x; t1 = v.y; t2 = v.z; t3 = v.w;
  } else {
    if (i0     < Nn) t0 = cnt[i0];
    if (i0 + 1 < Nn) t1 = cnt[i0 + 1];
    if (i0 + 2 < Nn) t2 = cnt[i0 + 2];
    if (i0 + 3 < Nn) t3 = cnt[i0 + 3];
  }
  int tsum = t0 + t1 + t2 + t3;
  int x = tsum;
#pragma unroll
  for (int d = 1; d < 64; d <<= 1) { int t = __shfl_up(x, d, 64); if (lane >= d) x += t; }
  if (lane == 63) wtot[wv] = x;
  __syncthreads();
  int wo = 0;
  for (int k = 0; k < wv; ++k) wo += wtot[k];
  int base = boff[blockIdx.x] + wo + x - tsum;
  if (i0     < Nn) { row_start[i0] = base; cursor[i0] = base; }
  if (i0 + 1 < Nn) { int v = base + t0;           row_start[i0 + 1] = v; cursor[i0 + 1] = v; }
  if (i0 + 2 < Nn) { int v = base + t0 + t1;      row_start[i0 + 2] = v; cursor[i0 + 2] = v; }
  if (i0 + 3 < Nn) { int v = base + t0 + t1 + t2; row_start[i0 + 3] = v; cursor[i0 + 3] = v; }
  if (blockIdx.x == 0 && tid == 0) row_start[Nn] = E;
}

__global__ void fill_k(const int* __restrict__ src, const int* __restrict__ dst,
                       int* __restrict__ cursor, int* __restrict__ csr, int E) {
  int i = blockIdx.x * blockDim.x + threadIdx.x;
  if (i < E) { int p = atomicAdd(&cursor[dst[i]], 1); csr[p] = src[i]; }
}

// ---------------- weight convert to bf16 ----------------
// Wb layout: [W0 l0..l2][W1 l0..l2][pW1][pW2], each 128x128
__global__ __launch_bounds__(256)
void wconv_k(const float* __restrict__ W0, const float* __restrict__ W1,
             const float* __restrict__ pW1, const float* __restrict__ pW2,
             bf16* __restrict__ Wb) {
  int idx = (blockIdx.x * 256 + threadIdx.x) * 4;
  int seg = idx >> 14, loc = idx & 16383;
  const float* srcp = seg < 3 ? W0 + (size_t)seg * 16384
                    : seg < 6 ? W1 + (size_t)(seg - 3) * 16384
                    : seg == 6 ? pW1 : pW2;
  float4 v = *(const float4*)(srcp + loc);
  union { bf16 h[4]; unsigned long long u; } pk;
  pk.h[0] = (bf16)v.x; pk.h[1] = (bf16)v.y; pk.h[2] = (bf16)v.z; pk.h[3] = (bf16)v.w;
  *(unsigned long long*)(Wb + idx) = pk.u;
}

// ---------------- aggregation (+z, bf16 output), unroll-4 ----------------
// MODE 0: h = H raw.  MODE 1: h = relu(a3*relu(a2*x+c2)+c3), coefs from accum slots
template<int MODE>
__global__ __launch_bounds__(256)
void agg_k(const float* __restrict__ H,
           const float* __restrict__ ac1, const float* __restrict__ g1, const float* __restrict__ b1,
           const float* __restrict__ ac2, const float* __restrict__ g2, const float* __restrict__ b2,
           float invN,
           const int* __restrict__ row_start, const int* __restrict__ csr,
           bf16* __restrict__ Z, int Nn) {
  __shared__ float sA2[128], sC2[128], sA3[128], sC3[128];
  int tid = threadIdx.x;
  if (MODE) {
    if (tid < 128) {
      float mu = ac1[tid] * invN;
      float var = fmaxf(ac1[128 + tid] * invN - mu * mu, 0.f);
      float a = g1[tid] * rsqrtf(var + BN_EPS);
      sA2[tid] = a; sC2[tid] = fmaf(-a, mu, b1[tid]);
      mu = ac2[tid] * invN;
      var = fmaxf(ac2[128 + tid] * invN - mu * mu, 0.f);
      a = g2[tid] * rsqrtf(var + BN_EPS);
      sA3[tid] = a; sC3[tid] = fmaf(-a, mu, b2[tid]);
    }
    __syncthreads();
  }
  int wv = tid >> 6, lane = tid & 63;
  int n = blockIdx.x * 4 + wv;
  if (n >= Nn) return;
  int c0 = lane * 2;
  float A2x = 0, A2y = 0, C2x = 0, C2y = 0, A3x = 0, A3y = 0, C3x = 0, C3y = 0;
  if (MODE) {
    A2x = sA2[c0]; A2y = sA2[c0 + 1]; C2x = sC2[c0]; C2y = sC2[c0 + 1];
    A3x = sA3[c0]; A3y = sA3[c0 + 1]; C3x = sC3[c0]; C3y = sC3[c0 + 1];
  }
  int beg = row_start[n], end = row_start[n + 1];
  float2 hn = *(const float2*)(H + (size_t)n * HID + c0);
  float inv = 1.f / fmaxf((float)(end - beg), 1.f);
  float ax0 = 0, ay0 = 0, ax1 = 0, ay1 = 0, ax2 = 0, ay2 = 0, ax3 = 0, ay3 = 0;
  int j = beg;
  for (; j + 4 <= end; j += 4) {
    int s0 = csr[j], s1 = csr[j + 1], s2 = csr[j + 2], s3 = csr[j + 3];
    float2 v0 = *(const float2*)(H + (size_t)s0 * HID + c0);
    float2 v1 = *(const float2*)(H + (size_t)s1 * HID + c0);
    float2 v2 = *(const float2*)(H + (size_t)s2 * HID + c0);
    float2 v3 = *(const float2*)(H + (size_t)s3 * HID + c0);
    if (MODE) {
      v0.x = bnrelu(bnrelu(v0.x, A2x, C2x), A3x, C3x);
      v0.y = bnrelu(bnrelu(v0.y, A2y, C2y), A3y, C3y);
      v1.x = bnrelu(bnrelu(v1.x, A2x, C2x), A3x, C3x);
      v1.y = bnrelu(bnrelu(v1.y, A2y, C2y), A3y, C3y);
      v2.x = bnrelu(bnrelu(v2.x, A2x, C2x), A3x, C3x);
      v2.y = bnrelu(bnrelu(v2.y, A2y, C2y), A3y, C3y);
      v3.x = bnrelu(bnrelu(v3.x, A2x, C2x), A3x, C3x);
      v3.y = bnrelu(bnrelu(v3.y, A2y, C2y), A3y, C3y);
    }
    ax0 += v0.x; ay0 += v0.y; ax1 += v1.x; ay1 += v1.y;
    ax2 += v2.x; ay2 += v2.y; ax3 += v3.x; ay3 += v3.y;
  }
  for (; j < end; ++j) {
    int s = csr[j];
    float2 v = *(const float2*)(H + (size_t)s * HID + c0);
    if (MODE) {
      v.x = bnrelu(bnrelu(v.x, A2x, C2x), A3x, C3x);
      v.y = bnrelu(bnrelu(v.y, A2y, C2y), A3y, C3y);
    }
    ax0 += v.x; ay0 += v.y;
  }
  float ax = (ax0 + ax1) + (ax2 + ax3);
  float ay = (ay0 + ay1) + (ay2 + ay3);
  float hx = hn.x, hy = hn.y;
  if (MODE) {
    hx = bnrelu(bnrelu(hx, A2x, C2x), A3x, C3x);
    hy = bnrelu(bnrelu(hy, A2y, C2y), A3y, C3y);
  }
  float zx = hx + ax * inv, zy = hy + ay * inv;
  union { bf16 h[2]; unsigned u; } pk;
  pk.h[0] = (bf16)zx; pk.h[1] = (bf16)zy;
  *(unsigned*)((char*)Z + ((size_t)n * HID + c0) * 2) = pk.u;
}

// ---------------- GEMM: C = A @ W^T, bf16 weights, fused column stats ----------------
// AMODE 0: A bf16 (Z). AMODE 1: A f32 + relu(a*x+c) transform (coefs from acIn), then bf16.
template<int AMODE>
__global__ __launch_bounds__(256)
void gemm_k(const void* __restrict__ Asrc,
            const float* __restrict__ acIn, const float* __restrict__ g, const float* __restrict__ b,
            float invN,
            const bf16* __restrict__ Wb, float* __restrict__ C,
            float* __restrict__ accumOut, int Nrows) {
  __shared__ float sA[128], sC[128], sSum[128], sSq[128];
  int tid = threadIdx.x;
  if (tid < 128) {
    sSum[tid] = 0.f; sSq[tid] = 0.f;
    if (AMODE) {
      float mu = acIn[tid] * invN;
      float var = fmaxf(acIn[128 + tid] * invN - mu * mu, 0.f);
      float a = g[tid] * rsqrtf(var + BN_EPS);
      sA[tid] = a; sC[tid] = fmaf(-a, mu, b[tid]);
    }
  }
  __syncthreads();
  int wv = tid >> 6, lane = tid & 63;
  int lm = lane & 15, lg = lane >> 4;
  int rowbase = blockIdx.x * 128 + wv * 32;
  f32x4 acc[2][8] = {};
#pragma unroll
  for (int kk = 0; kk < 4; ++kk) {
    int kb = kk * 32 + lg * 8;
    bf16x8 af[2];
    if (AMODE == 0) {
      const bf16* Zp = (const bf16*)Asrc;
#pragma unroll
      for (int rt = 0; rt < 2; ++rt) {
        int row = rowbase + rt * 16 + lm; if (row > Nrows - 1) row = Nrows - 1;
        af[rt] = *(const bf16x8*)(Zp + (size_t)row * HID + kb);
      }
    } else {
      const float* Tp = (const float*)Asrc;
      float4 a0 = *(const float4*)(sA + kb), a1 = *(const float4*)(sA + kb + 4);
      float4 q0 = *(const float4*)(sC + kb), q1 = *(const float4*)(sC + kb + 4);
#pragma unroll
      for (int rt = 0; rt < 2; ++rt) {
        int row = rowbase + rt * 16 + lm; if (row > Nrows - 1) row = Nrows - 1;
        const float* p = Tp + (size_t)row * HID + kb;
        float4 x0 = *(const float4*)p, x1 = *(const float4*)(p + 4);
        bf16x8 f;
        f[0] = (bf16)bnrelu(x0.x, a0.x, q0.x); f[1] = (bf16)bnrelu(x0.y, a0.y, q0.y);
        f[2] = (bf16)bnrelu(x0.z, a0.z, q0.z); f[3] = (bf16)bnrelu(x0.w, a0.w, q0.w);
        f[4] = (bf16)bnrelu(x1.x, a1.x, q1.x); f[5] = (bf16)bnrelu(x1.y, a1.y, q1.y);
        f[6] = (bf16)bnrelu(x1.z, a1.z, q1.z); f[7] = (bf16)bnrelu(x1.w, a1.w, q1.w);
        af[rt] = f;
      }
    }
    bf16x8 bfr[8];
#pragma unroll
    for (int ct = 0; ct < 8; ++ct)
      bfr[ct] = *(const bf16x8*)(Wb + (size_t)(ct * 16 + lm) * HID + kb);
#pragma unroll
    for (int rt = 0; rt < 2; ++rt)
#pragma unroll
      for (int ct = 0; ct < 8; ++ct)
        acc[rt][ct] = __builtin_amdgcn_mfma_f32_16x16x32_bf16(af[rt], bfr[ct], acc[rt][ct], 0, 0, 0);
  }
  // epilogue: store + per-column stats
#pragma unroll
  for (int ct = 0; ct < 8; ++ct) {
    int col = ct * 16 + lm;
    float ps = 0.f, pq = 0.f;
#pragma unroll
    for (int rt = 0; rt < 2; ++rt) {
#pragma unroll
      for (int i = 0; i < 4; ++i) {
        int row = rowbase + rt * 16 + lg * 4 + i;
        if (row < Nrows) {
          float v = acc[rt][ct][i];
          C[(size_t)row * HID + col] = v;
          ps += v; pq = fmaf(v, v, pq);
        }
      }
    }
    ps += __shfl_xor(ps, 16, 64); ps += __shfl_xor(ps, 32, 64);
    pq += __shfl_xor(pq, 16, 64); pq += __shfl_xor(pq, 32, 64);
    if (lane < 16) { atomicAdd(&sSum[col], ps); atomicAdd(&sSq[col], pq); }
  }
  __syncthreads();
  if (tid < 128) {
    atomicAdd(&accumOut[tid], sSum[tid]);
    atomicAdd(&accumOut[128 + tid], sSq[tid]);
  }
}

// ---------------- stats of relu(a*x+c) (outer BN input), coefs inline ----------------
__global__ __launch_bounds__(256)
void stats1_k(const float* __restrict__ T, const float* __restrict__ acIn,
              const float* __restrict__ g, const float* __restrict__ b, float invN,
              float* __restrict__ accumOut, int Nrows) {
  int col = threadIdx.x & 127, half = threadIdx.x >> 7;
  float mu = acIn[col] * invN;
  float var = fmaxf(acIn[128 + col] * invN - mu * mu, 0.f);
  float av = g[col] * rsqrtf(var + BN_EPS);
  float cv = fmaf(-av, mu, b[col]);
  float s = 0.f, sq = 0.f;
  for (int r = blockIdx.x * 2 + half; r < Nrows; r += gridDim.x * 2) {
    float x = T[(size_t)r * HID + col];
    x = fmaxf(fmaf(av, x, cv), 0.f);
    s += x; sq = fmaf(x, x, sq);
  }
  __shared__ float sb[256], qb[256];
  sb[threadIdx.x] = s; qb[threadIdx.x] = sq;
  __syncthreads();
  if (half == 0) {
    s += sb[threadIdx.x + 128]; sq += qb[threadIdx.x + 128];
    atomicAdd(&accumOut[col], s); atomicAdd(&accumOut[128 + col], sq);
  }
}

// ---------------- fused link predictor ----------------
__global__ __launch_bounds__(256)
void pred_k(const float* __restrict__ T, const float* __restrict__ acIn,
            const float* __restrict__ g, const float* __restrict__ b, float invN,
            const int* __restrict__ ps, const int* __restrict__ pd,
            const int* __restrict__ ns, const int* __restrict__ nd,
            const bf16* __restrict__ W1b, const float* __restrict__ b1p,
            const bf16* __restrict__ W2b, const float* __restrict__ b2p,
            const float* __restrict__ w3, const float* __restrict__ b3,
            float* __restrict__ out, int Pn) {
  __shared__ bf16 At[128 * 128];  // 32KB, XOR-swizzled
  __shared__ float sAp[128], sCp[128];
  int tid = threadIdx.x;
  if (tid < 128) {
    float mu = acIn[tid] * invN;
    float var = fmaxf(acIn[128 + tid] * invN - mu * mu, 0.f);
    float a = g[tid] * rsqrtf(var + BN_EPS);
    sAp[tid] = a; sCp[tid] = fmaf(-a, mu, b[tid]);
  }
  __syncthreads();
  int q0 = blockIdx.x * 128;
  {
    int r = tid >> 1;
    int q = q0 + r;
    int cb = (tid & 1) * 64;
    if (q < 2 * Pn) {
      int s, d;
      if (q < Pn) { s = ps[q]; d = pd[q]; } else { s = ns[q - Pn]; d = nd[q - Pn]; }
      const float* rs_ = T + (size_t)s * HID;
      const float* rd_ = T + (size_t)d * HID;
      for (int c = cb; c < cb + 64; c += 4) {
        float4 xs = *(const float4*)(rs_ + c);
        float4 xd = *(const float4*)(rd_ + c);
        float4 av = *(const float4*)(sAp + c);
        float4 cv = *(const float4*)(sCp + c);
        float t0 = bnrelu(xs.x, av.x, cv.x) * bnrelu(xd.x, av.x, cv.x);
        float t1 = bnrelu(xs.y, av.y, cv.y) * bnrelu(xd.y, av.y, cv.y);
        float t2 = bnrelu(xs.z, av.z, cv.z) * bnrelu(xd.z, av.z, cv.z);
        float t3 = bnrelu(xs.w, av.w, cv.w) * bnrelu(xd.w, av.w, cv.w);
        union { bf16 h[4]; unsigned long long u; } pk;
        pk.h[0] = (bf16)t0; pk.h[1] = (bf16)t1; pk.h[2] = (bf16)t2; pk.h[3] = (bf16)t3;
        unsigned addr = (unsigned)(r * 256 + c * 2);
        addr ^= (unsigned)((r & 7) << 4);
        *(unsigned long long*)((char*)At + addr) = pk.u;
      }
    } else {
      for (int c = cb; c < cb + 64; c += 4) {
        unsigned addr = (unsigned)(r * 256 + c * 2);
        addr ^= (unsigned)((r & 7) << 4);
        *(unsigned long long*)((char*)At + addr) = 0ull;
      }
    }
  }
  __syncthreads();
  int wv = tid >> 6, lane = tid & 63;
  int lm = lane & 15, lg = lane >> 4;
  const f32x4 vzero = {0.f, 0.f, 0.f, 0.f};
  f32x4 acc[2][8];
#pragma unroll
  for (int r = 0; r < 2; ++r) for (int c = 0; c < 8; ++c) acc[r][c] = vzero;
  // ---- layer 1 ----
#pragma unroll
  for (int kk = 0; kk < 4; ++kk) {
    bf16x8 af[2];
#pragma unroll
    for (int rt = 0; rt < 2; ++rt) {
      int row = wv * 32 + rt * 16 + lm;
      unsigned addr = (unsigned)(row * 256 + kk * 64 + lg * 16);
      addr ^= (unsigned)((row & 7) << 4);
      af[rt] = *(const bf16x8*)((char*)At + addr);
    }
    bf16x8 bfr[8];
#pragma unroll
    for (int ct = 0; ct < 8; ++ct)
      bfr[ct] = *(const bf16x8*)(W1b + (size_t)(ct * 16 + lm) * HID + kk * 32 + lg * 8);
#pragma unroll
    for (int rt = 0; rt < 2; ++rt)
#pragma unroll
      for (int ct = 0; ct < 8; ++ct)
        acc[rt][ct] = __builtin_amdgcn_mfma_f32_16x16x32_bf16(af[rt], bfr[ct], acc[rt][ct], 0, 0, 0);
  }
  __syncthreads();   // all LDS reads of stage-A done before overwrite
#pragma unroll
  for (int rt = 0; rt < 2; ++rt)
#pragma unroll
    for (int ct = 0; ct < 8; ++ct) {
      int col = ct * 16 + lm;
      float bb = b1p[col];
#pragma unroll
      for (int i = 0; i < 4; ++i) {
        int row = wv * 32 + rt * 16 + lg * 4 + i;
        float v = fmaxf(acc[rt][ct][i] + bb, 0.f);
        unsigned addr = (unsigned)(row * 256 + col * 2);
        addr ^= (unsigned)((row & 7) << 4);
        *(bf16*)((char*)At + addr) = (bf16)v;
      }
    }
  __syncthreads();
  // ---- layer 2 ----
#pragma unroll
  for (int r = 0; r < 2; ++r) for (int c = 0; c < 8; ++c) acc[r][c] = vzero;
#pragma unroll
  for (int kk = 0; kk < 4; ++kk) {
    bf16x8 af[2];
#pragma unroll
    for (int rt = 0; rt < 2; ++rt) {
      int row = wv * 32 + rt * 16 + lm;
      unsigned addr = (unsigned)(row * 256 + kk * 64 + lg * 16);
      addr ^= (unsigned)((row & 7) << 4);
      af[rt] = *(const bf16x8*)((char*)At + addr);
    }
    bf16x8 bfr[8];
#pragma unroll
    for (int ct = 0; ct < 8; ++ct)
      bfr[ct] = *(const bf16x8*)(W2b + (size_t)(ct * 16 + lm) * HID + kk * 32 + lg * 8);
#pragma unroll
    for (int rt = 0; rt < 2; ++rt)
#pragma unroll
      for (int ct = 0; ct < 8; ++ct)
        acc[rt][ct] = __builtin_amdgcn_mfma_f32_16x16x32_bf16(af[rt], bfr[ct], acc[rt][ct], 0, 0, 0);
  }
  // ---- w3 dot + reduce ----
  float b2v[8], w3v[8];
#pragma unroll
  for (int ct = 0; ct < 8; ++ct) { b2v[ct] = b2p[ct * 16 + lm]; w3v[ct] = w3[ct * 16 + lm]; }
  float b3s = b3[0];
#pragma unroll
  for (int rt = 0; rt < 2; ++rt) {
#pragma unroll
    for (int i = 0; i < 4; ++i) {
      float p = 0.f;
#pragma unroll
      for (int ct = 0; ct < 8; ++ct)
        p += fmaxf(acc[rt][ct][i] + b2v[ct], 0.f) * w3v[ct];
      p += __shfl_xor(p, 1); p += __shfl_xor(p, 2);
      p += __shfl_xor(p, 4); p += __shfl_xor(p, 8);
      int row = wv * 32 + rt * 16 + lg * 4 + i;
      int q = q0 + row;
      if (lm == 0 && q < 2 * Pn) out[q] = p + b3s;
    }
  }
}

// ---------------- launcher ----------------
extern "C" void kernel_launch(void* const* d_in, const int* in_sizes, int n_in,
                              void* d_out, int out_size, void* d_ws, size_t ws_size,
                              hipStream_t stream) {
  const float* x  = (const float*)d_in[0];
  const int* src  = (const int*)d_in[1];
  const int* dst  = (const int*)d_in[2];
  const int* ps   = (const int*)d_in[3];
  const int* pd   = (const int*)d_in[4];
  const int* ns   = (const int*)d_in[5];
  const int* nd   = (const int*)d_in[6];
  const float* W0 = (const float*)d_in[7];
  const float* W1 = (const float*)d_in[8];
  const float* g_mlp   = (const float*)d_in[9];
  const float* b_mlp   = (const float*)d_in[10];
  const float* g_apply = (const float*)d_in[11];
  const float* b_apply = (const float*)d_in[12];
  const float* g_out   = (const float*)d_in[13];
  const float* b_out   = (const float*)d_in[14];
  const float* pW1 = (const float*)d_in[15];
  const float* pb1 = (const float*)d_in[16];
  const float* pW2 = (const float*)d_in[17];
  const float* pb2 = (const float*)d_in[18];
  const float* pW3 = (const float*)d_in[19];
  const float* pb3 = (const float*)d_in[20];
  float* out = (float*)d_out;

  const int N = in_sizes[0] / HID;
  const int E = in_sizes[1];
  const int P = in_sizes[3];

  char* w = (char*)d_ws;
  size_t off = 0;
  auto alloc = [&](size_t bytes) -> void* {
    void* p = w + off;
    off = (off + bytes + 255) & ~(size_t)255;
    return p;
  };
  bf16*  Z  = (bf16*)alloc((size_t)N * HID * 2);
  float* TA = (float*)alloc((size_t)N * HID * 4);
  float* TB = (float*)alloc((size_t)N * HID * 4);
  int*   csr = (int*)alloc((size_t)E * 4);
  int*   row_start = (int*)alloc((size_t)(N + 1) * 4);
  size_t zoff = off;
  int*   cnt    = (int*)alloc((size_t)N * 4);
  float* accum  = (float*)alloc(9 * 256 * 4);
  size_t zbytes = off - zoff;
  int*   cursor = (int*)alloc((size_t)N * 4);
  int*   bsum   = (int*)alloc(256 * 4);
  bf16*  Wb     = (bf16*)alloc(8 * 16384 * 2);
  (void)ws_size; (void)n_in; (void)out_size;

  const int G = (N + 1023) / 1024;
  const float invN = 1.f / (float)N;

  hipMemsetAsync(w + zoff, 0, zbytes, stream);
  int gridE = (E + 255) / 256;
  hist_k<<<gridE, 256, 0, stream>>>(dst, cnt, E);
  scan1_k<<<G, 256, 0, stream>>>(cnt, bsum, N);
  scan2_k<<<1, 64, 0, stream>>>(bsum, G);
  scan3_k<<<G, 256, 0, stream>>>(cnt, bsum, row_start, cursor, N, E);
  fill_k<<<gridE, 256, 0, stream>>>(src, dst, cursor, csr, E);
  wconv_k<<<128, 256, 0, stream>>>(W0, W1, pW1, pW2, Wb);

  int gridN4 = (N + 3) / 4;
  int gridG  = (N + 127) / 128;

  for (int l = 0; l < 3; ++l) {
    int s0 = l * 3 + 0, s1 = l * 3 + 1, s2 = l * 3 + 2;
    if (l == 0)
      agg_k<0><<<gridN4, 256, 0, stream>>>(x, nullptr, nullptr, nullptr,
                                           nullptr, nullptr, nullptr, invN,
                                           row_start, csr, Z, N);
    else {
      int p1 = (l - 1) * 3 + 1, p2 = (l - 1) * 3 + 2;
      agg_k<1><<<gridN4, 256, 0, stream>>>(TB,
                                           accum + p1 * 256, g_apply + (l - 1) * HID, b_apply + (l - 1) * HID,
                                           accum + p2 * 256, g_out + (l - 1) * HID, b_out + (l - 1) * HID,
                                           invN, row_start, csr, Z, N);
    }
    gemm_k<0><<<gridG, 256, 0, stream>>>(Z, nullptr, nullptr, nullptr, invN,
                                         Wb + (size_t)l * 16384, TA, accum + s0 * 256, N);
    gemm_k<1><<<gridG, 256, 0, stream>>>(TA, accum + s0 * 256, g_mlp + l * HID, b_mlp + l * HID, invN,
                                         Wb + (size_t)(3 + l) * 16384, TB, accum + s1 * 256, N);
    if (l < 2)
      stats1_k<<<512, 256, 0, stream>>>(TB, accum + s1 * 256, g_apply + l * HID, b_apply + l * HID,
                                        invN, accum + s2 * 256, N);
  }
  int gridP = (2 * P + 127) / 128;
  pred_k<<<gridP, 256, 0, stream>>>(TB, accum + 7 * 256, g_apply + 2 * HID, b_apply + 2 * HID, invN,
                                    ps, pd, ns, nd,
                                    Wb + (size_t)6 * 16384, pb1,
                                    Wb + (size_t)7 * 16384, pb2,
                                    pW3, pb3, out, P);
}